// Round 11
// baseline (1003.004 us; speedup 1.0000x reference)
//
#include <hip/hip_runtime.h>

#define DEVINL static __device__ __forceinline__
// A wave's LDS ops are serviced in issue order (in-order lgkm for DS), so
// same-wave WAR/RAW through LDS needs only a compiler reorder fence.
#define CFENCE() asm volatile("" ::: "memory")

typedef float v2f __attribute__((ext_vector_type(2)));

DEVINL v2f mk2(float a, float b) { v2f r; r.x = a; r.y = b; return r; }
// One V_PK_FMA_F32: two IEEE fp32 FMAs per lane per issue.
DEVINL v2f pkfma(v2f a, v2f b, v2f c) { return __builtin_elementwise_fma(a, b, c); }

constexpr float KE = 2.885390081777927f;   // 2*log2(e)

#if __has_builtin(__builtin_amdgcn_exp2f)
DEVINL float exp2_fast(float x) { return __builtin_amdgcn_exp2f(x); }
#else
DEVINL float exp2_fast(float x) { return __expf(x * 0.6931471805599453f); }
#endif

// tanh(x) with t = x*2*log2(e) pre-folded into weights: 1 - 2/(2^t+1).
DEVINL float tanh_pre(float t) {
  float e = exp2_fast(t);
  return 1.0f - 2.0f * __builtin_amdgcn_rcpf(e + 1.0f);
}

template <int CTRL>
DEVINL float dpp_add(float v) {
  int t = __builtin_amdgcn_update_dpp(0, __float_as_int(v), CTRL, 0xF, 0xF, true);
  return v + __int_as_float(t);
}
// Sum across each 32-lane half-wave; result replicated within the half.
DEVINL float rsum32(float v) {
  v = dpp_add<0xB1>(v);    // quad_perm [1,0,3,2]
  v = dpp_add<0x4E>(v);    // quad_perm [2,3,0,1]
  v = dpp_add<0x141>(v);   // row_half_mirror
  v = dpp_add<0x140>(v);   // row_mirror
  v += __int_as_float(__builtin_amdgcn_ds_swizzle(__float_as_int(v), 0x401F)); // xor16
  return v;
}

// 32-wide dot vs an LDS row (uniform address per half), packed fp32.
DEVINL float dot32(const float* hrow, const v2f* W, float bias) {
  const float4* hp = (const float4*)hrow;
  v2f a0 = mk2(bias, 0.f), a1 = mk2(0.f, 0.f);
  v2f a2 = mk2(0.f, 0.f), a3 = mk2(0.f, 0.f);
#pragma unroll
  for (int q = 0; q < 8; q += 2) {
    float4 x = hp[q], y = hp[q + 1];
    a0 = pkfma(mk2(x.x, x.y), W[2 * q + 0], a0);
    a1 = pkfma(mk2(x.z, x.w), W[2 * q + 1], a1);
    a2 = pkfma(mk2(y.x, y.y), W[2 * q + 2], a2);
    a3 = pkfma(mk2(y.z, y.w), W[2 * q + 3], a3);
  }
  v2f s = (a0 + a1) + (a2 + a3);
  return s.x + s.y;
}
// 16-wide partial dot (k-split r3 layer 1), packed fp32.
DEVINL float pdot16(const float* hrow, const v2f* W) {
  const float4* hp = (const float4*)hrow;
  v2f a0 = mk2(0.f, 0.f), a1 = mk2(0.f, 0.f);
  float4 x = hp[0], y = hp[1];
  a0 = pkfma(mk2(x.x, x.y), W[0], a0);
  a1 = pkfma(mk2(x.z, x.w), W[1], a1);
  a0 = pkfma(mk2(y.x, y.y), W[2], a0);
  a1 = pkfma(mk2(y.z, y.w), W[3], a1);
  x = hp[2]; y = hp[3];
  a0 = pkfma(mk2(x.x, x.y), W[4], a0);
  a1 = pkfma(mk2(x.z, x.w), W[5], a1);
  a0 = pkfma(mk2(y.x, y.y), W[6], a0);
  a1 = pkfma(mk2(y.z, y.w), W[7], a1);
  v2f s = a0 + a1;
  return s.x + s.y;
}

constexpr int TSTEPS = 256;

// wave = 2 batch elements (ILP-interleaved streams); lanes 0-31 = r1 duties,
// lanes 32-63 = r2. Weights shared between streams. grid 2048 -> 2 waves/EU.
__global__ __attribute__((amdgpu_flat_work_group_size(64, 64)))
__attribute__((amdgpu_waves_per_eu(2, 2))) void reac_kernel(
    const float* __restrict__ useq,   // [B][T] f32
    const float* __restrict__ xz0,    // [B][26] f32
    const float* __restrict__ r1W0, const float* __restrict__ r1b0,
    const float* __restrict__ r1W1, const float* __restrict__ r1b1,
    const float* __restrict__ r1W2, const float* __restrict__ r1b2,
    const float* __restrict__ r2W0, const float* __restrict__ r2b0,
    const float* __restrict__ r2W1, const float* __restrict__ r2b1,
    const float* __restrict__ r2W2, const float* __restrict__ r2b2,
    const float* __restrict__ r3W0, const float* __restrict__ r3b0,
    const float* __restrict__ r3W1, const float* __restrict__ r3b1,
    const float* __restrict__ r3W2, const float* __restrict__ r3b2,
    float2* __restrict__ out)         // [B][T] -> (x0,x1) f32
{
  const int lane = threadIdx.x;
  const int j = lane & 31;
  const bool hi = lane >= 32;      // high half = r2 net
  const int b0 = blockIdx.x * 2;
  const int xaddr = ((lane ^ 32) << 2);   // ds_bpermute partner address

  auto xchg = [&](float v) -> float {
    return __int_as_float(__builtin_amdgcn_ds_bpermute(xaddr, __float_as_int(v)));
  };

  // ---- per-half net weights (column j), tanh prescale KE folded in ----
  const float* W0p = hi ? r2W0 : r1W0;
  const float* B0p = hi ? r2b0 : r1b0;
  const float* W1p = hi ? r2W1 : r1W1;
  const float* B1p = hi ? r2b1 : r1b1;
  const float* W2p = hi ? r2W2 : r1W2;
  const float* B2p = hi ? r2b2 : r1b2;
  const float sc = hi ? 0.2f : 0.3f;
  float w0K = W0p[j] * KE, b0K = B0p[j] * KE;
  float b1K = B1p[j] * KE;
  float w2sc = W2p[j] * sc, b2sc = B2p[0] * sc;

  v2f W1v[16];
#pragma unroll
  for (int k = 0; k < 16; ++k)
    W1v[k] = mk2(W1p[(2 * k) * 32 + j] * KE, W1p[(2 * k + 1) * 32 + j] * KE);

  v2f W0Cv[12];
#pragma unroll
  for (int m = 0; m < 12; ++m)
    W0Cv[m] = mk2(r3W0[(2 * m) * 32 + j] * KE, r3W0[(2 * m + 1) * 32 + j] * KE);
  const int kbase = hi ? 16 : 0;
  v2f W1Cv[8];
#pragma unroll
  for (int k = 0; k < 8; ++k)
    W1Cv[k] = mk2(r3W1[(kbase + 2 * k) * 32 + j] * KE,
                  r3W1[(kbase + 2 * k + 1) * 32 + j] * KE);
  float b0CK = r3b0[j] * KE, b1CK = r3b1[j] * KE;
  float w2C02 = r3W2[j] * 0.2f;
  float b2Cs = r3b2[0] * 0.2f - 0.05f;   // folds -F/V*0.5 of dCb

  __shared__ __align__(16) float zs[2][24];      // z state per stream
  __shared__ __align__(16) float zb[2][16];      // z4 prefix per stream
  __shared__ __align__(16) float h12[2][2][32];  // [stream][net][neuron]
  __shared__ __align__(16) float hR3[2][3][32];  // [stream][eval][neuron]

  float x0[2], x1[2], u[2];
#pragma unroll
  for (int s = 0; s < 2; ++s) {
    x0[s] = xz0[(b0 + s) * 26 + 0];
    x1[s] = xz0[(b0 + s) * 26 + 1];
    if (!hi && j < 24) zs[s][j] = xz0[(b0 + s) * 26 + 2 + j];
    u[s] = useq[(b0 + s) * TSTEPS];
  }
  CFENCE();

  // RK stage for BOTH streams (ops pairwise adjacent for ILP).
  auto stage2 = [&](const float* sxv, const float* syv, const float* rcp_,
                    const float* CafF, float* kx, float* ky) {
    CFENCE();                      // WAR: previous readers of h12 done
#pragma unroll
    for (int s = 0; s < 2; ++s) {
      float sv = hi ? syv[s] : sxv[s];
      h12[s][hi][j] = tanh_pre(fmaf(sv, w0K, b0K));
    }
    CFENCE();                      // RAW: writes before broadcast reads
    float r[2];
#pragma unroll
    for (int s = 0; s < 2; ++s) {
      float a = dot32(&h12[s][hi][0], W1v, b1K);
      r[s] = rsum32(tanh_pre(a) * w2sc) + b2sc;
    }
#pragma unroll
    for (int s = 0; s < 2; ++s) {
      float rp = xchg(r[s]);
      float ra = hi ? rp : r[s];
      float rb = hi ? r[s] : rp;
      float dCa = fmaf(-0.03f, sxv[s], CafF[s]) - ra;
      float dCb = fmaf(-0.02f, syv[s], fmaf(-3.0f, rb, ra) + rcp_[s]);
      kx[s] = dCa * (1.0f / 0.3f);
      ky[s] = dCb * (1.0f / 0.2f);
    }
  };

  for (int t = 0; t < TSTEPS; ++t) {
    int tn = (t < TSTEPS - 1) ? (t + 1) : t;
    float u_nxt[2], CafF[2];
#pragma unroll
    for (int s = 0; s < 2; ++s) {
      u_nxt[s] = useq[(b0 + s) * TSTEPS + tn];
      CafF[s] = fmaf(u[s], 0.05f, 0.05f);
    }

    if (lane < 2) {
      float a = lane ? x0[1] : x0[0];
      float c = lane ? x1[1] : x1[0];
      out[(b0 + lane) * TSTEPS + t] = make_float2(a, c);
    }

    CFENCE();
    if (!hi && j < 16) {
#pragma unroll
      for (int s = 0; s < 2; ++s)
        zb[s][j] = (j < 14) ? zs[s][j + 2] : ((j == 14) ? x0[s] : x1[s]);
    }
    CFENCE();

    // ---- r3 x3 per stream: low computes A(z), high computes A(z4) ----
    float A[2];
#pragma unroll
    for (int s = 0; s < 2; ++s) {
      const float4* zp = (const float4*)(hi ? &zb[s][0] : &zs[s][0]);
      float4 z0 = zp[0], z1 = zp[1], z2 = zp[2], z3 = zp[3];
      const float4* up = (const float4*)&zs[s][16];
      float4 u0 = up[0], u1 = up[1];
      v2f aa = mk2(b0CK, 0.f), ab = mk2(0.f, 0.f);
      aa = pkfma(mk2(z0.x, z0.y), W0Cv[0], aa);
      ab = pkfma(mk2(z0.z, z0.w), W0Cv[1], ab);
      aa = pkfma(mk2(z1.x, z1.y), W0Cv[2], aa);
      ab = pkfma(mk2(z1.z, z1.w), W0Cv[3], ab);
      aa = pkfma(mk2(z2.x, z2.y), W0Cv[4], aa);
      ab = pkfma(mk2(z2.z, z2.w), W0Cv[5], ab);
      aa = pkfma(mk2(z3.x, z3.y), W0Cv[6], aa);
      ab = pkfma(mk2(z3.z, z3.w), W0Cv[7], ab);
      aa = pkfma(mk2(u0.x, u0.y), W0Cv[8], aa);
      ab = pkfma(mk2(u0.z, u0.w), W0Cv[9], ab);
      aa = pkfma(mk2(u1.x, u1.y), W0Cv[10], aa);
      ab = pkfma(mk2(u1.z, u1.w), W0Cv[11], ab);
      v2f as = aa + ab;
      A[s] = as.x + as.y;
    }
#pragma unroll
    for (int s = 0; s < 2; ++s) {
      float Ap = xchg(A[s]);
      float tA = tanh_pre(A[s]);
      if (!hi) {
        hR3[s][0][j] = tA;
        hR3[s][1][j] = tanh_pre(0.5f * (A[s] + Ap));  // z23 by exact linearity
      } else {
        hR3[s][2][j] = tA;
      }
    }
    CFENCE();
    float rc1[2], rc23[2], rc4[2];
#pragma unroll
    for (int s = 0; s < 2; ++s) {
      float p0 = pdot16(&hR3[s][0][kbase], W1Cv);
      float p1 = pdot16(&hR3[s][1][kbase], W1Cv);
      float p2 = pdot16(&hR3[s][2][kbase], W1Cv);
      float o0 = p0 + xchg(p0) + b1CK;
      float o1 = p1 + xchg(p1) + b1CK;
      float o2 = p2 + xchg(p2) + b1CK;
      rc1[s]  = rsum32(tanh_pre(o0) * w2C02) + b2Cs;   // = rc - 0.05
      rc23[s] = rsum32(tanh_pre(o1) * w2C02) + b2Cs;
      rc4[s]  = rsum32(tanh_pre(o2) * w2C02) + b2Cs;
    }

    // ---- RK stages ----
    float kx1[2], ky1[2], kx2[2], ky2[2], kx3[2], ky3[2], kx4[2], ky4[2];
    stage2(x0, x1, rc1, CafF, kx1, ky1);
    float sx[2], sy[2];
#pragma unroll
    for (int s = 0; s < 2; ++s) {
      sx[s] = fmaf(kx1[s], 0.5f, x0[s]);
      sy[s] = fmaf(ky1[s], 0.5f, x1[s]);
    }
    stage2(sx, sy, rc23, CafF, kx2, ky2);
#pragma unroll
    for (int s = 0; s < 2; ++s) {
      sx[s] = fmaf(kx2[s], 0.5f, x0[s]);
      sy[s] = fmaf(ky2[s], 0.5f, x1[s]);
    }
    stage2(sx, sy, rc23, CafF, kx3, ky3);
#pragma unroll
    for (int s = 0; s < 2; ++s) {
      sx[s] = x0[s] + kx3[s];
      sy[s] = x1[s] + ky3[s];
    }
    stage2(sx, sy, rc4, CafF, kx4, ky4);

    // ---- state update: zplus = [xpseq[2:], x, upseq[1:], u] ----
    float znew[2];
    bool updz = (!hi) && (j < 24);
    if (updz) {
#pragma unroll
      for (int s = 0; s < 2; ++s)
        znew[s] = (j < 16) ? zb[s][j] : ((j < 23) ? zs[s][j + 1] : u[s]);
    }
    CFENCE();                      // reads ordered before overwrite
    if (updz) {
#pragma unroll
      for (int s = 0; s < 2; ++s) zs[s][j] = znew[s];
    }
#pragma unroll
    for (int s = 0; s < 2; ++s) {
      x0[s] += (kx1[s] + 2.0f * (kx2[s] + kx3[s]) + kx4[s]) * (1.0f / 6.0f);
      x1[s] += (ky1[s] + 2.0f * (ky2[s] + ky3[s]) + ky4[s]) * (1.0f / 6.0f);
      u[s] = u_nxt[s];
    }
    CFENCE();                      // zs writes ordered before next-iter reads
  }
}

extern "C" void kernel_launch(void* const* d_in, const int* in_sizes, int n_in,
                              void* d_out, int out_size, void* d_ws, size_t ws_size,
                              hipStream_t stream) {
  const float* p[20];
  for (int i = 0; i < 20; ++i) p[i] = (const float*)d_in[i];
  reac_kernel<<<dim3(2048), dim3(64), 0, stream>>>(
      p[0], p[1], p[2], p[3], p[4], p[5], p[6], p[7], p[8], p[9], p[10],
      p[11], p[12], p[13], p[14], p[15], p[16], p[17], p[18], p[19],
      (float2*)d_out);
}